// Round 5
// baseline (900.209 us; speedup 1.0000x reference)
//
#include <hip/hip_runtime.h>
#include <hip/hip_fp16.h>

#define NN 100000
#define NE 1200000
#define DIM 64
#define NBLK ((NN + 255) / 256)   // 391 level-1 scan blocks

// out = (0.5625 - 0.5*rD)*y + 0.5*rD*x + 0.5*inv0[d]*acc0 - 0.0625*inv1[d]*acc1
// acc_g = sum over graph-g edges of inv_g[src] * Y[src]
// Per-node float4 cf = (0.5625-0.5*rD, 0.5*rD, 0.5*inv0, -0.0625*inv1).

__global__ void deg_hist(const int* __restrict__ dst0, const int* __restrict__ dst1,
                         int* __restrict__ deg0, int* __restrict__ deg1) {
    int e = blockIdx.x * blockDim.x + threadIdx.x;
    if (e < NE) {
        atomicAdd(&deg0[dst0[e]], 1);
        atomicAdd(&deg1[dst1[e]], 1);
    }
}

// Dual exclusive scan of PADDED degrees (roundup8) -> rs0/rs1, dp0/dp1.
__global__ void __launch_bounds__(256) scan_l1(const int* __restrict__ deg0,
                                               const int* __restrict__ deg1,
                                               int* __restrict__ rs0, int* __restrict__ rs1,
                                               int* __restrict__ dp0, int* __restrict__ dp1,
                                               int* __restrict__ bs0, int* __restrict__ bs1) {
    __shared__ int s0[256], s1[256];
    int t = threadIdx.x;
    int n = blockIdx.x * 256 + t;
    int a = 0, b = 0;
    if (n < NN) {
        a = (deg0[n] + 7) & ~7;
        b = (deg1[n] + 7) & ~7;
    }
    s0[t] = a; s1[t] = b;
    __syncthreads();
    for (int off = 1; off < 256; off <<= 1) {
        int x0 = (t >= off) ? s0[t - off] : 0;
        int x1 = (t >= off) ? s1[t - off] : 0;
        __syncthreads();
        s0[t] += x0; s1[t] += x1;
        __syncthreads();
    }
    if (n < NN) {
        rs0[n] = s0[t] - a; dp0[n] = a;
        rs1[n] = s1[t] - b; dp1[n] = b;
    }
    if (t == 255) { bs0[blockIdx.x] = s0[255]; bs1[blockIdx.x] = s1[255]; }
}

__global__ void __launch_bounds__(512) scan_l2(int* __restrict__ bs0, int* __restrict__ bs1) {
    __shared__ int s0[512], s1[512];
    int t = threadIdx.x;
    int a = (t < NBLK) ? bs0[t] : 0;
    int b = (t < NBLK) ? bs1[t] : 0;
    s0[t] = a; s1[t] = b;
    __syncthreads();
    for (int off = 1; off < 512; off <<= 1) {
        int x0 = (t >= off) ? s0[t - off] : 0;
        int x1 = (t >= off) ? s1[t - off] : 0;
        __syncthreads();
        s0[t] += x0; s1[t] += x1;
        __syncthreads();
    }
    if (t < NBLK) { bs0[t] = s0[t] - a; bs1[t] = s1[t] - b; }
}

__global__ void __launch_bounds__(256) scan_l3(int* __restrict__ rs0, int* __restrict__ rs1,
                                               const int* __restrict__ bs0,
                                               const int* __restrict__ bs1) {
    int n = blockIdx.x * 256 + threadIdx.x;
    if (n < NN) {
        rs0[n] += bs0[blockIdx.x];
        rs1[n] += bs1[blockIdx.x];
    }
}

// inv arrays have NN+1 entries; inv[NN]=0 is the dummy node pad edges target.
__global__ void node_params(const int* __restrict__ deg0, const int* __restrict__ deg1,
                            float* __restrict__ inv0, float* __restrict__ inv1,
                            float4* __restrict__ cf) {
    int n = blockIdx.x * blockDim.x + threadIdx.x;
    if (n < NN) {
        int a = deg0[n], b = deg1[n];
        float i0 = (a > 0) ? rsqrtf((float)a) : 0.0f;
        float i1 = (b > 0) ? rsqrtf((float)b) : 0.0f;
        inv0[n] = i0; inv1[n] = i1;
        int s = a + b;
        float rD = (s > 0) ? 1.0f / (float)s : 0.0f;
        cf[n] = make_float4(0.5625f - 0.5f * rD, 0.5f * rD, 0.5f * i0, -0.0625f * i1);
    } else if (n == NN) {
        inv0[NN] = 0.0f; inv1[NN] = 0.0f;
    }
}

// Fill pad slots [deg, dp) of each node's CSR region with the dummy node NN.
__global__ void pad_fill(const int* __restrict__ deg0, const int* __restrict__ dp0,
                         const int* __restrict__ rs0, int* __restrict__ es0,
                         const int* __restrict__ deg1, const int* __restrict__ dp1,
                         const int* __restrict__ rs1, int* __restrict__ es1) {
    int n = blockIdx.x * blockDim.x + threadIdx.x;
    if (n < NN) {
        int b = rs0[n] + deg0[n], e = rs0[n] + dp0[n];
        for (int i = b; i < e; ++i) es0[i] = NN;
        b = rs1[n] + deg1[n]; e = rs1[n] + dp1[n];
        for (int i = b; i < e; ++i) es1[i] = NN;
    }
}

// 4-byte records: just the src index.
__global__ void scatter_edges(const int* __restrict__ src0, const int* __restrict__ dst0,
                              const int* __restrict__ src1, const int* __restrict__ dst1,
                              const int* __restrict__ rs0, const int* __restrict__ rs1,
                              int* __restrict__ cur0, int* __restrict__ cur1,
                              int* __restrict__ es0, int* __restrict__ es1) {
    int e = blockIdx.x * blockDim.x + threadIdx.x;
    if (e < NE) {
        int s = src0[e], d = dst0[e];
        int p = atomicAdd(&cur0[d], 1);
        es0[rs0[d] + p] = s;
        s = src1[e]; d = dst1[e];
        p = atomicAdd(&cur1[d], 1);
        es1[rs1[d] + p] = s;
    }
}

// x -> fp16 mirror (step 0's gather source).
__global__ void convert_x(const float* __restrict__ X, __half* __restrict__ Xh) {
    int i = blockIdx.x * blockDim.x + threadIdx.x;
    if (i < NN * DIM / 4) {
        float4 v = ((const float4*)X)[i];
        ushort4 o;
        o.x = __half_as_ushort(__float2half(v.x));
        o.y = __half_as_ushort(__float2half(v.y));
        o.z = __half_as_ushort(__float2half(v.z));
        o.w = __half_as_ushort(__float2half(v.w));
        ((ushort4*)Xh)[i] = o;
    }
}

// One wave per node (64 lanes = 64 features); 4 nodes / 256-thread block.
// Self/X/output trajectory in f32; neighbor gathers from the fp16 mirror.
// Edge records + inv weights are wave-uniform (scalar path); only the
// 128B row gather is vector.
__global__ void __launch_bounds__(256) step_kernel(
    const float* __restrict__ Yf, const __half* __restrict__ Yh,
    const float* __restrict__ X,
    const int* __restrict__ rs0, const int* __restrict__ dp0,
    const int* __restrict__ es0, const float* __restrict__ inv0,
    const int* __restrict__ rs1, const int* __restrict__ dp1,
    const int* __restrict__ es1, const float* __restrict__ inv1,
    const float4* __restrict__ cf,
    float* __restrict__ Yfo, __half* __restrict__ Yho)
{
    int node = blockIdx.x * 4 + (threadIdx.x >> 6);  // NN % 4 == 0, no bounds check
    int d = threadIdx.x & 63;
    int un = __builtin_amdgcn_readfirstlane(node);

    float acc0 = 0.0f;
    {
        int s = __builtin_amdgcn_readfirstlane(rs0[un]);
        int c = __builtin_amdgcn_readfirstlane(dp0[un]);
        for (int i = 0; i < c; i += 8) {
            int e[8];
#pragma unroll
            for (int k = 0; k < 8; ++k) e[k] = es0[s + i + k];
            float w[8];
#pragma unroll
            for (int k = 0; k < 8; ++k) w[k] = inv0[e[k]];
            float yv[8];
#pragma unroll
            for (int k = 0; k < 8; ++k) yv[k] = __half2float(Yh[e[k] * DIM + d]);
#pragma unroll
            for (int k = 0; k < 8; ++k) acc0 = fmaf(yv[k], w[k], acc0);
        }
    }
    float acc1 = 0.0f;
    {
        int s = __builtin_amdgcn_readfirstlane(rs1[un]);
        int c = __builtin_amdgcn_readfirstlane(dp1[un]);
        for (int i = 0; i < c; i += 8) {
            int e[8];
#pragma unroll
            for (int k = 0; k < 8; ++k) e[k] = es1[s + i + k];
            float w[8];
#pragma unroll
            for (int k = 0; k < 8; ++k) w[k] = inv1[e[k]];
            float yv[8];
#pragma unroll
            for (int k = 0; k < 8; ++k) yv[k] = __half2float(Yh[e[k] * DIM + d]);
#pragma unroll
            for (int k = 0; k < 8; ++k) acc1 = fmaf(yv[k], w[k], acc1);
        }
    }
    float4 cc = cf[un];
    float y  = Yf[(size_t)un * DIM + d];
    float xx = X[(size_t)un * DIM + d];
    float o = cc.x * y + cc.y * xx + cc.z * acc0 + cc.w * acc1;
    Yfo[(size_t)un * DIM + d] = o;
    if (Yho) Yho[(size_t)un * DIM + d] = __float2half(o);
}

extern "C" void kernel_launch(void* const* d_in, const int* in_sizes, int n_in,
                              void* d_out, int out_size, void* d_ws, size_t ws_size,
                              hipStream_t stream) {
    const float* x   = (const float*)d_in[0];
    const int* src0  = (const int*)d_in[1];
    const int* dst0  = (const int*)d_in[2];
    const int* src1  = (const int*)d_in[3];
    const int* dst1  = (const int*)d_in[4];
    float* out = (float*)d_out;

    char* ws = (char*)d_ws;
    size_t off = 0;
    auto alloc = [&](size_t bytes) -> void* {
        void* p = ws + off;
        off += (bytes + 255) & ~(size_t)255;
        return p;
    };

    const size_t ES_CAP = (size_t)NE + 8 * NN;  // per-graph padded-CSR bound

    float*  W    = (float*)alloc((size_t)NN * DIM * 4);        // f32 ping (out = pong)
    __half* HA   = (__half*)alloc((size_t)(NN + 1) * DIM * 2); // fp16 mirror A (starts = xh)
    __half* HB   = (__half*)alloc((size_t)(NN + 1) * DIM * 2); // fp16 mirror B
    int*    es0  = (int*)alloc(ES_CAP * 4);
    int*    es1  = (int*)alloc(ES_CAP * 4);
    int*    cnt  = (int*)alloc((size_t)4 * NN * 4);  // deg0,deg1,cur0,cur1 one memset
    int*    deg0 = cnt;
    int*    deg1 = cnt + NN;
    int*    cur0 = cnt + 2 * NN;
    int*    cur1 = cnt + 3 * NN;
    int*    rs0  = (int*)alloc((size_t)NN * 4);
    int*    rs1  = (int*)alloc((size_t)NN * 4);
    int*    dp0  = (int*)alloc((size_t)NN * 4);
    int*    dp1  = (int*)alloc((size_t)NN * 4);
    float*  inv0 = (float*)alloc((size_t)(NN + 1) * 4);
    float*  inv1 = (float*)alloc((size_t)(NN + 1) * 4);
    float4* cf   = (float4*)alloc((size_t)NN * 16);
    int*    bs0  = (int*)alloc((size_t)NBLK * 4);
    int*    bs1  = (int*)alloc((size_t)NBLK * 4);

    hipMemsetAsync(cnt, 0, (size_t)4 * NN * 4, stream);

    const int TB = 256;
    deg_hist<<<(NE + TB - 1) / TB, TB, 0, stream>>>(dst0, dst1, deg0, deg1);
    scan_l1<<<NBLK, 256, 0, stream>>>(deg0, deg1, rs0, rs1, dp0, dp1, bs0, bs1);
    scan_l2<<<1, 512, 0, stream>>>(bs0, bs1);
    scan_l3<<<NBLK, 256, 0, stream>>>(rs0, rs1, bs0, bs1);
    node_params<<<(NN + 1 + TB - 1) / TB, TB, 0, stream>>>(deg0, deg1, inv0, inv1, cf);
    pad_fill<<<(NN + TB - 1) / TB, TB, 0, stream>>>(deg0, dp0, rs0, es0,
                                                    deg1, dp1, rs1, es1);
    scatter_edges<<<(NE + TB - 1) / TB, TB, 0, stream>>>(src0, dst0, src1, dst1,
                                                         rs0, rs1, cur0, cur1, es0, es1);
    convert_x<<<(NN * DIM / 4 + TB - 1) / TB, TB, 0, stream>>>(x, HA);

    int grid = NN / 4;  // 4 nodes per block
    const float* curF = x;
    for (int i = 0; i < 8; ++i) {
        float*  dstF = (i & 1) ? out : W;
        const __half* hin = (i & 1) ? HB : HA;
        __half* hout = (i == 7) ? (__half*)nullptr : ((i & 1) ? HA : HB);
        step_kernel<<<grid, TB, 0, stream>>>(curF, hin, x,
                                             rs0, dp0, es0, inv0,
                                             rs1, dp1, es1, inv1,
                                             cf, dstF, hout);
        curF = dstF;
    }
}

// Round 6
// 548.538 us; speedup vs baseline: 1.6411x; 1.6411x over previous
//
#include <hip/hip_runtime.h>
#include <hip/hip_fp16.h>

#define NN 100000
#define NE 1200000
#define DIM 64
#define NBINS 391                 // bin = dst >> 8  (256 nodes per bin)
#define NBE 128                   // edge-partition blocks
#define CHUNK (NE / NBE)          // 9375, exact
#define NBLK ((NN + 255) / 256)   // 391 scan blocks

// out = (0.5625 - 0.5*rD)*y + 0.5*rD*x + sum_e w_e * Y[src_e]
//   g0 edge: w = +0.5    * inv0[dst]*inv0[src]
//   g1 edge: w = -0.0625 * inv1[dst]*inv1[src]

// ---------- binned edge partition ----------
// record in binned[]: x = src, y = dst | (g<<20)

__global__ void __launch_bounds__(256) bin_count(const int* __restrict__ dst0,
                                                 const int* __restrict__ dst1,
                                                 int* __restrict__ blk_cnt) {
    __shared__ int c[NBINS];
    int t = threadIdx.x;
    for (int i = t; i < NBINS; i += 256) c[i] = 0;
    __syncthreads();
    int lo = blockIdx.x * CHUNK, hi = lo + CHUNK;
    for (int e = lo + t; e < hi; e += 256) {
        atomicAdd(&c[dst0[e] >> 8], 1);
        atomicAdd(&c[dst1[e] >> 8], 1);
    }
    __syncthreads();
    for (int i = t; i < NBINS; i += 256) blk_cnt[blockIdx.x * NBINS + i] = c[i];
}

// 1 block: bin totals (sum over NBE blocks) -> exclusive scan -> bin_start[NBINS+1]
__global__ void __launch_bounds__(512) bin_scan(const int* __restrict__ blk_cnt,
                                                int* __restrict__ bin_start) {
    __shared__ int tot[512];
    int t = threadIdx.x;
    int s = 0;
    if (t < NBINS)
        for (int b = 0; b < NBE; ++b) s += blk_cnt[b * NBINS + t];
    tot[t] = s;
    __syncthreads();
    for (int off = 1; off < 512; off <<= 1) {
        int v = (t >= off) ? tot[t - off] : 0;
        __syncthreads();
        tot[t] += v;
        __syncthreads();
    }
    if (t <= NBINS) bin_start[t] = tot[t] - s;  // s==0 for t>=NBINS -> total at t==NBINS
}

// One block per bin: scan this bin's column of blk_cnt over NBE blocks.
__global__ void __launch_bounds__(NBE) blk_base_k(const int* __restrict__ blk_cnt,
                                                  const int* __restrict__ bin_start,
                                                  int* __restrict__ blk_base) {
    __shared__ int s[NBE];
    int b = blockIdx.x, t = threadIdx.x;
    int v = blk_cnt[t * NBINS + b];
    s[t] = v;
    __syncthreads();
    for (int off = 1; off < NBE; off <<= 1) {
        int x = (t >= off) ? s[t - off] : 0;
        __syncthreads();
        s[t] += x;
        __syncthreads();
    }
    blk_base[t * NBINS + b] = bin_start[b] + s[t] - v;  // exclusive
}

__global__ void __launch_bounds__(256) bin_permute(const int* __restrict__ src0,
                                                   const int* __restrict__ dst0,
                                                   const int* __restrict__ src1,
                                                   const int* __restrict__ dst1,
                                                   const int* __restrict__ blk_base,
                                                   int2* __restrict__ binned) {
    __shared__ int off[NBINS];
    int t = threadIdx.x;
    for (int i = t; i < NBINS; i += 256) off[i] = blk_base[blockIdx.x * NBINS + i];
    __syncthreads();
    int lo = blockIdx.x * CHUNK, hi = lo + CHUNK;
    for (int e = lo + t; e < hi; e += 256) {
        int s = src0[e], d = dst0[e];
        int p = atomicAdd(&off[d >> 8], 1);
        binned[p] = make_int2(s, d);
        s = src1[e]; d = dst1[e];
        p = atomicAdd(&off[d >> 8], 1);
        binned[p] = make_int2(s, d | (1 << 20));
    }
}

// One block per bin: per-node degree counts via LDS (no global atomics).
__global__ void __launch_bounds__(256) deg_count(const int2* __restrict__ binned,
                                                 const int* __restrict__ bin_start,
                                                 int* __restrict__ deg0,
                                                 int* __restrict__ deg1) {
    __shared__ int dg[512];  // [local node 0..255][g]
    int b = blockIdx.x, t = threadIdx.x;
    dg[t] = 0; dg[t + 256] = 0;
    __syncthreads();
    int lo = bin_start[b], hi = bin_start[b + 1];
    for (int i = lo + t; i < hi; i += 256) {
        int2 r = binned[i];
        int d = r.y & 0xFFFFF, g = r.y >> 20;
        atomicAdd(&dg[((d & 255) << 1) | g], 1);
    }
    __syncthreads();
    int n = b * 256 + t;
    if (n < NN) { deg0[n] = dg[t << 1]; deg1[n] = dg[(t << 1) | 1]; }
}

// ---------- padded merged-degree scan ----------
__global__ void __launch_bounds__(256) scan_l1(const int* __restrict__ deg0,
                                               const int* __restrict__ deg1,
                                               int* __restrict__ rs, int* __restrict__ dp,
                                               int* __restrict__ bs) {
    __shared__ int s0[256];
    int t = threadIdx.x;
    int n = blockIdx.x * 256 + t;
    int a = 0;
    if (n < NN) a = (deg0[n] + deg1[n] + 7) & ~7;
    s0[t] = a;
    __syncthreads();
    for (int off = 1; off < 256; off <<= 1) {
        int x0 = (t >= off) ? s0[t - off] : 0;
        __syncthreads();
        s0[t] += x0;
        __syncthreads();
    }
    if (n < NN) { rs[n] = s0[t] - a; dp[n] = a; }
    if (t == 255) bs[blockIdx.x] = s0[255];
}

__global__ void __launch_bounds__(512) scan_l2(int* __restrict__ bs) {
    __shared__ int s0[512];
    int t = threadIdx.x;
    int a = (t < NBLK) ? bs[t] : 0;
    s0[t] = a;
    __syncthreads();
    for (int off = 1; off < 512; off <<= 1) {
        int x0 = (t >= off) ? s0[t - off] : 0;
        __syncthreads();
        s0[t] += x0;
        __syncthreads();
    }
    if (t < NBLK) bs[t] = s0[t] - a;
}

__global__ void __launch_bounds__(256) scan_l3(int* __restrict__ rs, const int* __restrict__ bs) {
    int n = blockIdx.x * 256 + threadIdx.x;
    if (n < NN) rs[n] += bs[blockIdx.x];
}

__global__ void node_params(const int* __restrict__ deg0, const int* __restrict__ deg1,
                            float* __restrict__ inv0, float* __restrict__ inv1,
                            float2* __restrict__ cf) {
    int n = blockIdx.x * blockDim.x + threadIdx.x;
    if (n < NN) {
        int a = deg0[n], b = deg1[n];
        float i0 = (a > 0) ? rsqrtf((float)a) : 0.0f;
        float i1 = (b > 0) ? rsqrtf((float)b) : 0.0f;
        inv0[n] = i0; inv1[n] = i1;
        int s = a + b;
        float rD = (s > 0) ? 1.0f / (float)s : 0.0f;
        cf[n] = make_float2(0.5625f - 0.5f * rD, 0.5f * rD);
    }
}

// Pad slots [degsum, dp) get {src=0, w=0}: harmless L2-hot gathers of row 0.
__global__ void pad_fill(const int* __restrict__ deg0, const int* __restrict__ deg1,
                         const int* __restrict__ dp, const int* __restrict__ rs,
                         int2* __restrict__ es) {
    int n = blockIdx.x * blockDim.x + threadIdx.x;
    if (n < NN) {
        int b = rs[n] + deg0[n] + deg1[n], e = rs[n] + dp[n];
        for (int i = b; i < e; ++i) es[i] = make_int2(0, 0);
    }
}

// One block per bin: fold weights, scatter into final CSR (bin-local writes).
__global__ void __launch_bounds__(256) csr_scatter(const int2* __restrict__ binned,
                                                   const int* __restrict__ bin_start,
                                                   const int* __restrict__ rs,
                                                   const float* __restrict__ inv0,
                                                   const float* __restrict__ inv1,
                                                   int2* __restrict__ es) {
    __shared__ int cur[256];
    int b = blockIdx.x, t = threadIdx.x;
    cur[t] = 0;
    __syncthreads();
    int lo = bin_start[b], hi = bin_start[b + 1];
    for (int i = lo + t; i < hi; i += 256) {
        int2 r = binned[i];
        int sN = r.x, d = r.y & 0xFFFFF, g = r.y >> 20;
        float w = g ? (-0.0625f * inv1[d] * inv1[sN]) : (0.5f * inv0[d] * inv0[sN]);
        int p = atomicAdd(&cur[d & 255], 1);
        es[rs[d] + p] = make_int2(sN, __float_as_int(w));
    }
}

__global__ void convert_x(const float* __restrict__ X, __half* __restrict__ Xh) {
    int i = blockIdx.x * blockDim.x + threadIdx.x;
    if (i < NN * DIM / 4) {
        float4 v = ((const float4*)X)[i];
        ushort4 o;
        o.x = __half_as_ushort(__float2half(v.x));
        o.y = __half_as_ushort(__float2half(v.y));
        o.z = __half_as_ushort(__float2half(v.z));
        o.w = __half_as_ushort(__float2half(v.w));
        ((ushort4*)Xh)[i] = o;
    }
}

// One wave per node; merged CSR; fp16 gathers; edge-record prefetch pipeline.
__global__ void __launch_bounds__(256) step_kernel(
    const float* __restrict__ Yf, const __half* __restrict__ Yh,
    const float* __restrict__ X,
    const int* __restrict__ rs, const int* __restrict__ dp,
    const int2* __restrict__ es, const float2* __restrict__ cf,
    float* __restrict__ Yfo, __half* __restrict__ Yho)
{
    int node = blockIdx.x * 4 + (threadIdx.x >> 6);  // NN % 4 == 0
    int d = threadIdx.x & 63;
    int un = __builtin_amdgcn_readfirstlane(node);
    int s  = __builtin_amdgcn_readfirstlane(rs[un]);
    int c  = __builtin_amdgcn_readfirstlane(dp[un]);

    float acc = 0.0f;
    int2 eb[8];
#pragma unroll
    for (int k = 0; k < 8; ++k) eb[k] = es[s + k];
    for (int i = 0; i < c; i += 8) {
        int2 en[8];
#pragma unroll
        for (int k = 0; k < 8; ++k) en[k] = es[s + i + 8 + k];  // prefetch (slack-padded)
        float yv[8];
#pragma unroll
        for (int k = 0; k < 8; ++k) yv[k] = __half2float(Yh[(size_t)eb[k].x * DIM + d]);
#pragma unroll
        for (int k = 0; k < 8; ++k) acc = fmaf(yv[k], __int_as_float(eb[k].y), acc);
#pragma unroll
        for (int k = 0; k < 8; ++k) eb[k] = en[k];
    }
    float2 cc = cf[un];
    float y  = Yf[(size_t)un * DIM + d];
    float xx = X[(size_t)un * DIM + d];
    float o = cc.x * y + cc.y * xx + acc;
    Yfo[(size_t)un * DIM + d] = o;
    if (Yho) Yho[(size_t)un * DIM + d] = __float2half(o);
}

extern "C" void kernel_launch(void* const* d_in, const int* in_sizes, int n_in,
                              void* d_out, int out_size, void* d_ws, size_t ws_size,
                              hipStream_t stream) {
    const float* x   = (const float*)d_in[0];
    const int* src0  = (const int*)d_in[1];
    const int* dst0  = (const int*)d_in[2];
    const int* src1  = (const int*)d_in[3];
    const int* dst1  = (const int*)d_in[4];
    float* out = (float*)d_out;

    char* ws = (char*)d_ws;
    size_t off = 0;
    auto alloc = [&](size_t bytes) -> void* {
        void* p = ws + off;
        off += (bytes + 255) & ~(size_t)255;
        return p;
    };

    const size_t ES_CAP = (size_t)2 * NE + 8 * NN + 64;  // padded CSR + prefetch slack

    float*  W    = (float*)alloc((size_t)NN * DIM * 4);        // f32 ping; ALSO aliases binned
    __half* HA   = (__half*)alloc((size_t)NN * DIM * 2);
    __half* HB   = (__half*)alloc((size_t)NN * DIM * 2);
    int2*   es   = (int2*)alloc(ES_CAP * 8);
    int*    blk_cnt  = (int*)alloc((size_t)NBE * NBINS * 4);
    int*    blk_base = (int*)alloc((size_t)NBE * NBINS * 4);
    int*    bin_st   = (int*)alloc((size_t)(NBINS + 1) * 4);
    int*    deg0 = (int*)alloc((size_t)NN * 4);
    int*    deg1 = (int*)alloc((size_t)NN * 4);
    int*    rs   = (int*)alloc((size_t)NN * 4);
    int*    dp   = (int*)alloc((size_t)NN * 4);
    float*  inv0 = (float*)alloc((size_t)NN * 4);
    float*  inv1 = (float*)alloc((size_t)NN * 4);
    float2* cf   = (float2*)alloc((size_t)NN * 8);
    int*    bs   = (int*)alloc((size_t)NBLK * 4);

    // binned (19.2 MB) aliases W (25.6 MB): dead before step 0 writes W.
    int2* binned = (int2*)W;

    const int TB = 256;
    bin_count<<<NBE, 256, 0, stream>>>(dst0, dst1, blk_cnt);
    bin_scan<<<1, 512, 0, stream>>>(blk_cnt, bin_st);
    blk_base_k<<<NBINS, NBE, 0, stream>>>(blk_cnt, bin_st, blk_base);
    bin_permute<<<NBE, 256, 0, stream>>>(src0, dst0, src1, dst1, blk_base, binned);
    deg_count<<<NBINS, 256, 0, stream>>>(binned, bin_st, deg0, deg1);
    scan_l1<<<NBLK, 256, 0, stream>>>(deg0, deg1, rs, dp, bs);
    scan_l2<<<1, 512, 0, stream>>>(bs);
    scan_l3<<<NBLK, 256, 0, stream>>>(rs, bs);
    node_params<<<(NN + TB - 1) / TB, TB, 0, stream>>>(deg0, deg1, inv0, inv1, cf);
    pad_fill<<<(NN + TB - 1) / TB, TB, 0, stream>>>(deg0, deg1, dp, rs, es);
    csr_scatter<<<NBINS, 256, 0, stream>>>(binned, bin_st, rs, inv0, inv1, es);
    convert_x<<<(NN * DIM / 4 + TB - 1) / TB, TB, 0, stream>>>(x, HA);

    int grid = NN / 4;
    const float* curF = x;
    for (int i = 0; i < 8; ++i) {
        float*  dstF = (i & 1) ? out : W;
        const __half* hin = (i & 1) ? HB : HA;
        __half* hout = (i == 7) ? (__half*)nullptr : ((i & 1) ? HA : HB);
        step_kernel<<<grid, TB, 0, stream>>>(curF, hin, x, rs, dp, es, cf, dstF, hout);
        curF = dstF;
    }
}